// Round 23
// baseline (210.203 us; speedup 1.0000x reference)
//
#include <hip/hip_runtime.h>
#include <hip/hip_bf16.h>
#include <math.h>

#define B_ 4
#define T_ 2048
#define E_ 768
#define H_ 3
#define D_ 256
#define LOG2E 1.4426950408889634f

typedef __attribute__((ext_vector_type(8))) _Float16 half8;
typedef __attribute__((ext_vector_type(8))) unsigned short ushort8;
typedef __attribute__((ext_vector_type(4))) float f32x4;

static __device__ inline unsigned short f2h(float x) {
    _Float16 h = (_Float16)x;
    return *reinterpret_cast<unsigned short*>(&h);
}

#define GLOAD_LDS(SRC, DST) \
    __builtin_amdgcn_global_load_lds( \
        (const __attribute__((address_space(1))) void*)(SRC), \
        (__attribute__((address_space(3))) void*)(DST), 16, 0, 0)

// ---------------------------------------------------------------------------
// All weight transposes in ONE dispatch (validated R10-R22).
// ---------------------------------------------------------------------------
__global__ __launch_bounds__(256)
void transpose_cast_all(const float* __restrict__ Wk, const float* __restrict__ Wq,
                        const float* __restrict__ Wv, const float* __restrict__ Wo,
                        unsigned short* __restrict__ WTk, unsigned short* __restrict__ WTq,
                        unsigned short* __restrict__ WTv, unsigned short* __restrict__ WoT)
{
    __shared__ float tile[32][33];
    const int z = blockIdx.z;
    const float* in; unsigned short* out; int R, C;
    if (z < 9) {
        const int mat = z / 3, hd = z % 3;
        R = E_; C = D_;
        in  = (mat == 0 ? Wk  : mat == 1 ? Wq  : Wv)  + (long)hd * E_ * D_;
        out = (mat == 0 ? WTk : mat == 1 ? WTq : WTv) + (long)hd * D_ * E_;
    } else {
        R = E_; C = E_;
        in = Wo; out = WoT;
    }
    const int c0 = blockIdx.x * 32;
    const int r0 = blockIdx.y * 32;
    if (c0 >= C) return;
    const int t  = threadIdx.x;
    const int cc = t & 31, rr = t >> 5;
    #pragma unroll
    for (int i = 0; i < 4; ++i)
        tile[rr + i * 8][cc] = in[(long)(r0 + rr + i * 8) * C + c0 + cc];
    __syncthreads();
    const int rr2 = t & 31, cc2 = t >> 5;
    #pragma unroll
    for (int i = 0; i < 4; ++i)
        out[(long)(c0 + cc2 + i * 8) * R + r0 + rr2] = f2h(tile[rr2][cc2 + i * 8]);
}

// ---------------------------------------------------------------------------
// fp16 MFMA GEMM body — R22 compute core + flash-validated SINGLE-BARRIER
// double-buffered pipeline (R13/R19 pattern):
//   iter kt: vmcnt(0) [tile-kt loads landed]
//            CONVA: cvt fA regs -> ds_write As[buf]; lgkmcnt(0)
//            s_barrier        [tile kt visible; buf^1 proven free]
//            issue tile kt+1  [B via global_load_lds; A via gload (f16) or
//                              reg-prefetch (fp32)]  -- covered by compute
//            compute tile kt from As[buf]/Bs[buf]
// Safety: barrier(kt-1) is after compute(kt-2) in every wave's program order
// -> As/Bs[buf] free when written/staged at iter kt; compute(kt-1) readers
// use buf^1 throughout. fA regs consumed (WRITE_A) before reissue.
// TRANSC writes C transposed (-> Vt).
// ---------------------------------------------------------------------------
template<bool CONVA, bool OUT16, bool TRANSC>
__device__ __forceinline__
void gemm_body(const float* Af, const unsigned short* Ah, const unsigned short* Bz,
               void* Cz, const float* bias, int K, int lda, int ldc,
               int m0, int n0, int tid)
{
    __shared__ unsigned short As[2][128 * 32];
    __shared__ unsigned short Bs[2][128 * 32];

    const int lane = tid & 63, wid = tid >> 6;
    const int wm = wid >> 1, wn = wid & 1;
    const int fr = lane & 15, fg = lane >> 4;
    const int NK = K >> 5;

    float4 fA[2][2];                       // CONVA reg-staging (16 VGPR)

    auto ISSUE_A = [&](int bufi, int k0) {
        #pragma unroll
        for (int i = 0; i < 2; ++i) {
            const int G = tid + i * 256;
            const int row = G >> 2, g = G & 3;
            if (CONVA) {
                const float* s = Af + (long)(m0 + row) * lda + k0 + g * 8;
                fA[i][0] = *(const float4*)s;
                fA[i][1] = *(const float4*)(s + 4);
            } else {
                GLOAD_LDS(Ah + (long)(m0 + row) * lda + k0 + g * 8,
                          &As[bufi][G * 8]);
            }
        }
    };
    auto ISSUE_B = [&](int bufi, int k0) {
        #pragma unroll
        for (int i = 0; i < 2; ++i) {
            const int G = tid + i * 256;
            const int row = G >> 2, g = G & 3;
            GLOAD_LDS(Bz + (long)(n0 + row) * K + k0 + g * 8,
                      &Bs[bufi][G * 8]);
        }
    };
    auto WRITE_A = [&](int bufi) {         // CONVA only: cvt regs -> LDS
        #pragma unroll
        for (int i = 0; i < 2; ++i) {
            const int G = tid + i * 256;
            ushort8 pa;
            pa[0] = f2h(fA[i][0].x); pa[1] = f2h(fA[i][0].y);
            pa[2] = f2h(fA[i][0].z); pa[3] = f2h(fA[i][0].w);
            pa[4] = f2h(fA[i][1].x); pa[5] = f2h(fA[i][1].y);
            pa[6] = f2h(fA[i][1].z); pa[7] = f2h(fA[i][1].w);
            *(ushort8*)&As[bufi][G * 8] = pa;
        }
    };

    f32x4 acc[4][4];
    #pragma unroll
    for (int mt = 0; mt < 4; ++mt)
        #pragma unroll
        for (int nt = 0; nt < 4; ++nt) acc[mt][nt] = (f32x4)(0.f);

    ISSUE_A(0, 0);
    ISSUE_B(0, 0);
    int buf = 0;
    for (int kt = 0; kt < NK; ++kt) {
        asm volatile("s_waitcnt vmcnt(0)" ::: "memory");
        __builtin_amdgcn_sched_barrier(0);
        if (CONVA) {
            WRITE_A(buf);
            asm volatile("s_waitcnt lgkmcnt(0)" ::: "memory");
            __builtin_amdgcn_sched_barrier(0);
        }
        __builtin_amdgcn_s_barrier();
        __builtin_amdgcn_sched_barrier(0);
        if (kt + 1 < NK) {
            ISSUE_A(buf ^ 1, (kt + 1) << 5);
            ISSUE_B(buf ^ 1, (kt + 1) << 5);
        }

        half8 a[4], b[4];
        #pragma unroll
        for (int mt = 0; mt < 4; ++mt)
            a[mt] = *(const half8*)&As[buf][(wm * 64 + mt * 16 + fr) * 32 + fg * 8];
        #pragma unroll
        for (int nt = 0; nt < 4; ++nt)
            b[nt] = *(const half8*)&Bs[buf][(wn * 64 + nt * 16 + fr) * 32 + fg * 8];
        #pragma unroll
        for (int mt = 0; mt < 4; ++mt)
            #pragma unroll
            for (int nt = 0; nt < 4; ++nt)
                acc[mt][nt] = __builtin_amdgcn_mfma_f32_16x16x32_f16(
                                  a[mt], b[nt], acc[mt][nt], 0, 0, 0);
        buf ^= 1;
    }

    #pragma unroll
    for (int nt = 0; nt < 4; ++nt) {
        const int col = n0 + wn * 64 + nt * 16 + fr;
        const float badd = bias ? bias[col] : 0.f;
        #pragma unroll
        for (int mt = 0; mt < 4; ++mt) {
            const int row = m0 + wm * 64 + mt * 16 + fg * 4;
            #pragma unroll
            for (int reg = 0; reg < 4; ++reg) {
                const float vv = acc[mt][nt][reg] + badd;
                if (TRANSC)
                    ((unsigned short*)Cz)[(long)col * ldc + row + reg] = f2h(vv);
                else if (OUT16)
                    ((unsigned short*)Cz)[(long)(row + reg) * ldc + col] = f2h(vv);
                else
                    ((float*)Cz)[(long)(row + reg) * ldc + col] = vv;
            }
        }
    }
}

template<bool CONVA, bool OUT16>
__global__ __launch_bounds__(256)
void gemm_mfma(const void* __restrict__ Av, const unsigned short* __restrict__ Bt,
               void* __restrict__ Cv, const float* __restrict__ bias,
               int K, int Hdiv, int lda, int ldc, long sA, long sB, long sC)
{
    const int z = blockIdx.z;
    const float*          Af = (const float*)Av          + (long)(z / Hdiv) * sA;
    const unsigned short* Ah = (const unsigned short*)Av + (long)(z / Hdiv) * sA;
    const unsigned short* Bz = Bt + (long)(z % Hdiv) * sB;
    void* Cz = OUT16 ? (void*)((unsigned short*)Cv + (long)z * sC)
                     : (void*)((float*)Cv + (long)z * sC);
    gemm_body<CONVA, OUT16, false>(Af, Ah, Bz, Cz, bias, K, lda, ldc,
                                   blockIdx.y * 128, blockIdx.x * 128, threadIdx.x);
}

// Fused K/V/Q projection; V written transposed directly into Vt [D][T].
__global__ __launch_bounds__(256)
void qkv_proj(const float* __restrict__ Xk, const float* __restrict__ Xv,
              const float* __restrict__ Xq,
              const unsigned short* __restrict__ WTk, const unsigned short* __restrict__ WTv,
              const unsigned short* __restrict__ WTq,
              unsigned short* __restrict__ Kp, unsigned short* __restrict__ Vt,
              unsigned short* __restrict__ Qp)
{
    const int z = blockIdx.z;
    const int which = z / 12, bh = z % 12;
    const int b = bh / H_, h = bh % H_;
    const int m0 = blockIdx.y * 128, n0 = blockIdx.x * 128;
    const int tid = threadIdx.x;
    if (which == 1) {
        const float* Af = Xv + (long)b * T_ * E_;
        const unsigned short* Bz = WTv + (long)h * D_ * E_;
        unsigned short* Cz = Vt + (long)bh * D_ * T_;
        gemm_body<true, true, true>(Af, nullptr, Bz, Cz, nullptr, E_, E_, T_, m0, n0, tid);
    } else {
        const float* X = (which == 0) ? Xk : Xq;
        const unsigned short* W = (which == 0) ? WTk : WTq;
        unsigned short* P = (which == 0) ? Kp : Qp;
        const float* Af = X + (long)b * T_ * E_;
        const unsigned short* Bz = W + (long)h * D_ * E_;
        unsigned short* Cz = P + (long)bh * T_ * D_;
        gemm_body<true, true, false>(Af, nullptr, Bz, Cz, nullptr, E_, E_, D_, m0, n0, tid);
    }
}

// ---------------------------------------------------------------------------
// BK=64 8-wave shared-staging flash attention (R19/R22, best validated: 93us).
// UNTOUCHED this round.
// ---------------------------------------------------------------------------
__global__ __launch_bounds__(512, 1)
void flash_lds(const unsigned short* __restrict__ Qb, const unsigned short* __restrict__ Kb,
               const unsigned short* __restrict__ Vtb, unsigned short* __restrict__ Z2h,
               float scale_log2e)
{
    __shared__ unsigned short Ktile[2][64 * 256];   // 64KB
    __shared__ unsigned short Vtile[2][256 * 64];   // 64KB
    __shared__ unsigned short Ps[8][16 * 72];       // 18KB

    const int p  = blockIdx.x;
    const int l  = (p & 7) * 24 + (p >> 3);    // 192 = 8*24, bijective
    const int bh = l >> 4;                     // <=2 bh per XCD chunk
    const int pi = l & 15;                     // 0 = heaviest, first in chunk
    const int b = bh / H_, h = bh % H_;
    const int tid = threadIdx.x;
    const int w = tid >> 6, lane = tid & 63;
    const int g = lane >> 4, fr = lane & 15;
    const int qw0 = (w < 4) ? (pi * 64 + w * 16) : ((31 - pi) * 64 + (w - 4) * 16);

    const unsigned short* kg = Kb  + (long)bh * T_ * D_;
    const unsigned short* vg = Vtb + (long)bh * D_ * T_;

    const unsigned short* qrow = Qb + ((long)bh * T_ + qw0 + fr) * D_;
    const _Float16 hs = (_Float16)scale_log2e;
    half8 qf[8];
    #pragma unroll
    for (int c = 0; c < 8; ++c) {
        qf[c] = *(const half8*)(qrow + c * 32 + g * 8);
        qf[c] *= hs;
    }

    f32x4 o[16];
    #pragma unroll
    for (int dt = 0; dt < 16; ++dt) o[dt] = (f32x4)(0.f);
    float mrow[4] = {-INFINITY, -INFINITY, -INFINITY, -INFINITY};
    float lrow[4] = {0.f, 0.f, 0.f, 0.f};

    const int nkt = 32 - pi;                   // 17..32 k-tiles of 64

    auto STAGE = [&](int bufi, int kt) {
        const int k0 = kt * 64;
        #pragma unroll
        for (int i = 0; i < 4; ++i) {              // K: 2048 granules / 512 thr
            const int L = tid + i * 512;
            const int r = L >> 5, cg = L & 31;
            GLOAD_LDS(kg + (long)(k0 + r) * D_ + ((cg ^ (r & 7)) * 8),
                      &Ktile[bufi][L * 8]);
        }
        #pragma unroll
        for (int i = 0; i < 4; ++i) {              // Vt: 2048 granules (8/row)
            const int L = tid + i * 512;
            const int dr = L >> 3, gq = L & 7;
            GLOAD_LDS(vg + (long)dr * T_ + k0 + ((gq ^ (dr & 7)) * 8),
                      &Vtile[bufi][L * 8]);
        }
    };

    STAGE(0, 0);
    int buf = 0;
    for (int kt = 0; kt < nkt; ++kt) {
        asm volatile("s_waitcnt vmcnt(0)" ::: "memory");    // tile kt (only in flight)
        __builtin_amdgcn_sched_barrier(0);
        __builtin_amdgcn_s_barrier();                        // buf^1 free, tile visible
        __builtin_amdgcn_sched_barrier(0);
        if (kt + 1 < nkt)
            STAGE(buf ^ 1, kt + 1);                          // covered by compute below

        const int k0 = kt * 64;
        if (k0 <= qw0 + 15) {
            // ---- QK^T: S[16q x 64k] ----
            f32x4 s[4];
            #pragma unroll
            for (int nt = 0; nt < 4; ++nt) s[nt] = (f32x4)(0.f);
            const int kkey = fr & 7;
            __builtin_amdgcn_s_setprio(1);
            #pragma unroll
            for (int c = 0; c < 8; ++c) {
                #pragma unroll
                for (int nt = 0; nt < 4; ++nt) {
                    const int kr = nt * 16 + fr;
                    half8 kf = *(const half8*)&Ktile[buf][(kr * 32 + ((c * 4 + g) ^ kkey)) * 8];
                    s[nt] = __builtin_amdgcn_mfma_f32_16x16x32_f16(qf[c], kf, s[nt], 0, 0, 0);
                }
            }
            __builtin_amdgcn_s_setprio(0);

            // ---- causal mask (log2 domain) ----
            const bool diag = (k0 + 63 > qw0);
            float sv[4][4];
            #pragma unroll
            for (int nt = 0; nt < 4; ++nt)
                #pragma unroll
                for (int reg = 0; reg < 4; ++reg) {
                    float v = s[nt][reg];
                    if (diag && (k0 + nt * 16 + fr > qw0 + g * 4 + reg)) v = -INFINITY;
                    sv[nt][reg] = v;
                }

            // ---- defer-max online softmax ----
            float pmax[4];
            #pragma unroll
            for (int reg = 0; reg < 4; ++reg)
                pmax[reg] = fmaxf(fmaxf(sv[0][reg], sv[1][reg]),
                                  fmaxf(sv[2][reg], sv[3][reg]));
            const bool ok = (pmax[0] <= mrow[0] + 8.f) && (pmax[1] <= mrow[1] + 8.f)
                         && (pmax[2] <= mrow[2] + 8.f) && (pmax[3] <= mrow[3] + 8.f);
            if (!__all(ok)) {
                #pragma unroll
                for (int reg = 0; reg < 4; ++reg) {
                    float tm = pmax[reg];
                    tm = fmaxf(tm, __shfl_xor(tm, 1));
                    tm = fmaxf(tm, __shfl_xor(tm, 2));
                    tm = fmaxf(tm, __shfl_xor(tm, 4));
                    tm = fmaxf(tm, __shfl_xor(tm, 8));
                    const float mnew = fmaxf(mrow[reg], tm);
                    const float alpha = exp2f(mrow[reg] - mnew);
                    mrow[reg] = mnew;
                    lrow[reg] *= alpha;
                    #pragma unroll
                    for (int dt = 0; dt < 16; ++dt) o[dt][reg] *= alpha;
                }
            }
            #pragma unroll
            for (int nt = 0; nt < 4; ++nt)
                #pragma unroll
                for (int reg = 0; reg < 4; ++reg) {
                    const float pp = exp2f(sv[nt][reg] - mrow[reg]);
                    lrow[reg] += pp;
                    Ps[w][(g * 4 + reg) * 72 + nt * 16 + fr] = f2h(pp);
                }

            // ---- P as A-frags (k 0..31 and 32..63) ----
            const half8 pf0 = *(const half8*)&Ps[w][fr * 72 + g * 8];
            const half8 pf1 = *(const half8*)&Ps[w][fr * 72 + 32 + g * 8];

            // ---- PV: O[16q x 256d] += P * V (two k-halves) ----
            __builtin_amdgcn_s_setprio(1);
            #pragma unroll
            for (int dt = 0; dt < 16; ++dt) {
                const int dr = dt * 16 + fr;
                const int key = dr & 7;
                half8 vf0 = *(const half8*)&Vtile[buf][(dr * 8 + (g ^ key)) * 8];
                o[dt] = __builtin_amdgcn_mfma_f32_16x16x32_f16(pf0, vf0, o[dt], 0, 0, 0);
                half8 vf1 = *(const half8*)&Vtile[buf][(dr * 8 + ((g + 4) ^ key)) * 8];
                o[dt] = __builtin_amdgcn_mfma_f32_16x16x32_f16(pf1, vf1, o[dt], 0, 0, 0);
            }
            __builtin_amdgcn_s_setprio(0);
        }
        buf ^= 1;
    }

    // ---- epilogue: reduce lrow across fr lanes, O /= l, write f16 ----
    float inv[4];
    #pragma unroll
    for (int reg = 0; reg < 4; ++reg) {
        float ps = lrow[reg];
        ps += __shfl_xor(ps, 1);
        ps += __shfl_xor(ps, 2);
        ps += __shfl_xor(ps, 4);
        ps += __shfl_xor(ps, 8);
        inv[reg] = 1.f / ps;
    }
    const long rowbase = ((long)b * T_ + qw0 + g * 4) * E_ + h * D_;
    #pragma unroll
    for (int reg = 0; reg < 4; ++reg) {
        unsigned short* dst = Z2h + rowbase + (long)reg * E_ + fr;
        #pragma unroll
        for (int dt = 0; dt < 16; ++dt)
            dst[dt * 16] = f2h(o[dt][reg] * inv[reg]);
    }
}

// ---------------------------------------------------------------------------
// d_in: keys, values, queries, Wk, Wq, Wv, Wo, bo (fp32)
// ws (f16): Kp|Vp(unused)|Qp|Vt | Z2h | weights
// ---------------------------------------------------------------------------
extern "C" void kernel_launch(void* const* d_in, const int* in_sizes, int n_in,
                              void* d_out, int out_size, void* d_ws, size_t ws_size,
                              hipStream_t stream)
{
    const float* Xk = (const float*)d_in[0];
    const float* Xv = (const float*)d_in[1];
    const float* Xq = (const float*)d_in[2];
    const float* Wk = (const float*)d_in[3];
    const float* Wq = (const float*)d_in[4];
    const float* Wv = (const float*)d_in[5];
    const float* Wo = (const float*)d_in[6];
    const float* bo = (const float*)d_in[7];
    float* out = (float*)d_out;

    const size_t phd = (size_t)B_ * H_ * T_ * D_;
    const size_t wsz = (size_t)H_ * E_ * D_;
    unsigned short* Kp  = (unsigned short*)d_ws;
    unsigned short* Vp  = Kp + phd;                 // unused
    unsigned short* Qp  = Vp + phd;
    unsigned short* Vt  = Qp + phd;
    unsigned short* Z2h = Vt + phd;
    unsigned short* WTk = Z2h + (size_t)B_ * T_ * E_;
    unsigned short* WTq = WTk + wsz;
    unsigned short* WTv = WTq + wsz;
    unsigned short* WoT = WTv + wsz;

    dim3 blk(256);

    dim3 gtw(E_ / 32, E_ / 32, 10);
    transpose_cast_all<<<gtw, blk, 0, stream>>>(Wk, Wq, Wv, Wo, WTk, WTq, WTv, WoT);

    dim3 gproj(D_ / 128, T_ / 128, 36);
    qkv_proj<<<gproj, blk, 0, stream>>>(Xk, Xv, Xq, WTk, WTv, WTq, Kp, Vt, Qp);

    // BK=64 8-wave flash attention -> Z2h f16 [B][T][H*D]
    dim3 gf(16 * B_ * H_);                          // 192 blocks x 8 waves
    dim3 fblk(512);
    flash_lds<<<gf, fblk, 0, stream>>>(Qp, Kp, Vt, Z2h,
                                       0.022097086912079608f * LOG2E);

    dim3 gout(E_ / 128, (B_ * T_) / 128, 1);
    gemm_mfma<false, false><<<gout, blk, 0, stream>>>(Z2h, WoT, out, bo, E_, 1, E_, E_,
                                                      0L, 0L, 0L);
}

// Round 24
// 178.425 us; speedup vs baseline: 1.1781x; 1.1781x over previous
//
#include <hip/hip_runtime.h>
#include <hip/hip_bf16.h>
#include <math.h>

#define B_ 4
#define T_ 2048
#define E_ 768
#define H_ 3
#define D_ 256
#define LOG2E 1.4426950408889634f

typedef __attribute__((ext_vector_type(8))) _Float16 half8;
typedef __attribute__((ext_vector_type(8))) unsigned short ushort8;
typedef __attribute__((ext_vector_type(4))) float f32x4;

static __device__ inline unsigned short f2h(float x) {
    _Float16 h = (_Float16)x;
    return *reinterpret_cast<unsigned short*>(&h);
}

#define GLOAD_LDS(SRC, DST) \
    __builtin_amdgcn_global_load_lds( \
        (const __attribute__((address_space(1))) void*)(SRC), \
        (__attribute__((address_space(3))) void*)(DST), 16, 0, 0)

// ---------------------------------------------------------------------------
// All weight transposes in ONE dispatch (validated R10-R22).
// ---------------------------------------------------------------------------
__global__ __launch_bounds__(256)
void transpose_cast_all(const float* __restrict__ Wk, const float* __restrict__ Wq,
                        const float* __restrict__ Wv, const float* __restrict__ Wo,
                        unsigned short* __restrict__ WTk, unsigned short* __restrict__ WTq,
                        unsigned short* __restrict__ WTv, unsigned short* __restrict__ WoT)
{
    __shared__ float tile[32][33];
    const int z = blockIdx.z;
    const float* in; unsigned short* out; int R, C;
    if (z < 9) {
        const int mat = z / 3, hd = z % 3;
        R = E_; C = D_;
        in  = (mat == 0 ? Wk  : mat == 1 ? Wq  : Wv)  + (long)hd * E_ * D_;
        out = (mat == 0 ? WTk : mat == 1 ? WTq : WTv) + (long)hd * D_ * E_;
    } else {
        R = E_; C = E_;
        in = Wo; out = WoT;
    }
    const int c0 = blockIdx.x * 32;
    const int r0 = blockIdx.y * 32;
    if (c0 >= C) return;
    const int t  = threadIdx.x;
    const int cc = t & 31, rr = t >> 5;
    #pragma unroll
    for (int i = 0; i < 4; ++i)
        tile[rr + i * 8][cc] = in[(long)(r0 + rr + i * 8) * C + c0 + cc];
    __syncthreads();
    const int rr2 = t & 31, cc2 = t >> 5;
    #pragma unroll
    for (int i = 0; i < 4; ++i)
        out[(long)(c0 + cc2 + i * 8) * R + r0 + rr2] = f2h(tile[rr2][cc2 + i * 8]);
}

// ---------------------------------------------------------------------------
// fp16 MFMA GEMM body (validated R6-R22; 32KB LDS -> ~5 blocks/CU TLP.
// R23's dbuf port doubled LDS -> 2 blocks/CU -> qkv_proj 2x slower: reverted).
// TRANSC writes C transposed (-> Vt).
// ---------------------------------------------------------------------------
template<bool CONVA, bool OUT16, bool TRANSC>
__device__ __forceinline__
void gemm_body(const float* Af, const unsigned short* Ah, const unsigned short* Bz,
               void* Cz, const float* bias, int K, int lda, int ldc,
               int m0, int n0, int tid)
{
    __shared__ unsigned short As[128 * 32];
    __shared__ unsigned short Bs[128 * 32];

    const int lane = tid & 63, wid = tid >> 6;
    const int wm = wid >> 1, wn = wid & 1;
    const int fr = lane & 15, fg = lane >> 4;

    f32x4 acc[4][4];
    #pragma unroll
    for (int mt = 0; mt < 4; ++mt)
        #pragma unroll
        for (int nt = 0; nt < 4; ++nt) acc[mt][nt] = (f32x4)(0.f);

    for (int k0 = 0; k0 < K; k0 += 32) {
        #pragma unroll
        for (int i = 0; i < 2; ++i) {
            const int G = tid + i * 256;
            const int row = G >> 2, g = G & 3;
            ushort8 pa;
            if (CONVA) {
                const float* s = Af + (long)(m0 + row) * lda + k0 + g * 8;
                float4 f0 = *(const float4*)s, f1 = *(const float4*)(s + 4);
                pa[0] = f2h(f0.x); pa[1] = f2h(f0.y); pa[2] = f2h(f0.z); pa[3] = f2h(f0.w);
                pa[4] = f2h(f1.x); pa[5] = f2h(f1.y); pa[6] = f2h(f1.z); pa[7] = f2h(f1.w);
            } else {
                pa = *(const ushort8*)(Ah + (long)(m0 + row) * lda + k0 + g * 8);
            }
            *(ushort8*)&As[row * 32 + g * 8] = pa;
            *(ushort8*)&Bs[row * 32 + g * 8] =
                *(const ushort8*)(Bz + (long)(n0 + row) * K + k0 + g * 8);
        }
        __syncthreads();

        half8 a[4], b[4];
        #pragma unroll
        for (int mt = 0; mt < 4; ++mt)
            a[mt] = *(const half8*)&As[(wm * 64 + mt * 16 + fr) * 32 + fg * 8];
        #pragma unroll
        for (int nt = 0; nt < 4; ++nt)
            b[nt] = *(const half8*)&Bs[(wn * 64 + nt * 16 + fr) * 32 + fg * 8];
        #pragma unroll
        for (int mt = 0; mt < 4; ++mt)
            #pragma unroll
            for (int nt = 0; nt < 4; ++nt)
                acc[mt][nt] = __builtin_amdgcn_mfma_f32_16x16x32_f16(
                                  a[mt], b[nt], acc[mt][nt], 0, 0, 0);
        __syncthreads();
    }

    #pragma unroll
    for (int nt = 0; nt < 4; ++nt) {
        const int col = n0 + wn * 64 + nt * 16 + fr;
        const float badd = bias ? bias[col] : 0.f;
        #pragma unroll
        for (int mt = 0; mt < 4; ++mt) {
            const int row = m0 + wm * 64 + mt * 16 + fg * 4;
            #pragma unroll
            for (int reg = 0; reg < 4; ++reg) {
                const float vv = acc[mt][nt][reg] + badd;
                if (TRANSC)
                    ((unsigned short*)Cz)[(long)col * ldc + row + reg] = f2h(vv);
                else if (OUT16)
                    ((unsigned short*)Cz)[(long)(row + reg) * ldc + col] = f2h(vv);
                else
                    ((float*)Cz)[(long)(row + reg) * ldc + col] = vv;
            }
        }
    }
}

template<bool CONVA, bool OUT16>
__global__ __launch_bounds__(256)
void gemm_mfma(const void* __restrict__ Av, const unsigned short* __restrict__ Bt,
               void* __restrict__ Cv, const float* __restrict__ bias,
               int K, int Hdiv, int lda, int ldc, long sA, long sB, long sC)
{
    const int z = blockIdx.z;
    const float*          Af = (const float*)Av          + (long)(z / Hdiv) * sA;
    const unsigned short* Ah = (const unsigned short*)Av + (long)(z / Hdiv) * sA;
    const unsigned short* Bz = Bt + (long)(z % Hdiv) * sB;
    void* Cz = OUT16 ? (void*)((unsigned short*)Cv + (long)z * sC)
                     : (void*)((float*)Cv + (long)z * sC);
    gemm_body<CONVA, OUT16, false>(Af, Ah, Bz, Cz, bias, K, lda, ldc,
                                   blockIdx.y * 128, blockIdx.x * 128, threadIdx.x);
}

// Fused K/V/Q projection; V written transposed directly into Vt [D][T].
__global__ __launch_bounds__(256)
void qkv_proj(const float* __restrict__ Xk, const float* __restrict__ Xv,
              const float* __restrict__ Xq,
              const unsigned short* __restrict__ WTk, const unsigned short* __restrict__ WTv,
              const unsigned short* __restrict__ WTq,
              unsigned short* __restrict__ Kp, unsigned short* __restrict__ Vt,
              unsigned short* __restrict__ Qp)
{
    const int z = blockIdx.z;
    const int which = z / 12, bh = z % 12;
    const int b = bh / H_, h = bh % H_;
    const int m0 = blockIdx.y * 128, n0 = blockIdx.x * 128;
    const int tid = threadIdx.x;
    if (which == 1) {
        const float* Af = Xv + (long)b * T_ * E_;
        const unsigned short* Bz = WTv + (long)h * D_ * E_;
        unsigned short* Cz = Vt + (long)bh * D_ * T_;
        gemm_body<true, true, true>(Af, nullptr, Bz, Cz, nullptr, E_, E_, T_, m0, n0, tid);
    } else {
        const float* X = (which == 0) ? Xk : Xq;
        const unsigned short* W = (which == 0) ? WTk : WTq;
        unsigned short* P = (which == 0) ? Kp : Qp;
        const float* Af = X + (long)b * T_ * E_;
        const unsigned short* Bz = W + (long)h * D_ * E_;
        unsigned short* Cz = P + (long)bh * T_ * D_;
        gemm_body<true, true, false>(Af, nullptr, Bz, Cz, nullptr, E_, E_, D_, m0, n0, tid);
    }
}

// ---------------------------------------------------------------------------
// BK=64 8-wave shared-staging flash attention (R19/R22, best validated: 93us).
// ---------------------------------------------------------------------------
__global__ __launch_bounds__(512, 1)
void flash_lds(const unsigned short* __restrict__ Qb, const unsigned short* __restrict__ Kb,
               const unsigned short* __restrict__ Vtb, unsigned short* __restrict__ Z2h,
               float scale_log2e)
{
    __shared__ unsigned short Ktile[2][64 * 256];   // 64KB
    __shared__ unsigned short Vtile[2][256 * 64];   // 64KB
    __shared__ unsigned short Ps[8][16 * 72];       // 18KB

    const int p  = blockIdx.x;
    const int l  = (p & 7) * 24 + (p >> 3);    // 192 = 8*24, bijective
    const int bh = l >> 4;                     // <=2 bh per XCD chunk
    const int pi = l & 15;                     // 0 = heaviest, first in chunk
    const int b = bh / H_, h = bh % H_;
    const int tid = threadIdx.x;
    const int w = tid >> 6, lane = tid & 63;
    const int g = lane >> 4, fr = lane & 15;
    const int qw0 = (w < 4) ? (pi * 64 + w * 16) : ((31 - pi) * 64 + (w - 4) * 16);

    const unsigned short* kg = Kb  + (long)bh * T_ * D_;
    const unsigned short* vg = Vtb + (long)bh * D_ * T_;

    const unsigned short* qrow = Qb + ((long)bh * T_ + qw0 + fr) * D_;
    const _Float16 hs = (_Float16)scale_log2e;
    half8 qf[8];
    #pragma unroll
    for (int c = 0; c < 8; ++c) {
        qf[c] = *(const half8*)(qrow + c * 32 + g * 8);
        qf[c] *= hs;
    }

    f32x4 o[16];
    #pragma unroll
    for (int dt = 0; dt < 16; ++dt) o[dt] = (f32x4)(0.f);
    float mrow[4] = {-INFINITY, -INFINITY, -INFINITY, -INFINITY};
    float lrow[4] = {0.f, 0.f, 0.f, 0.f};

    const int nkt = 32 - pi;                   // 17..32 k-tiles of 64

    auto STAGE = [&](int bufi, int kt) {
        const int k0 = kt * 64;
        #pragma unroll
        for (int i = 0; i < 4; ++i) {              // K: 2048 granules / 512 thr
            const int L = tid + i * 512;
            const int r = L >> 5, cg = L & 31;
            GLOAD_LDS(kg + (long)(k0 + r) * D_ + ((cg ^ (r & 7)) * 8),
                      &Ktile[bufi][L * 8]);
        }
        #pragma unroll
        for (int i = 0; i < 4; ++i) {              // Vt: 2048 granules (8/row)
            const int L = tid + i * 512;
            const int dr = L >> 3, gq = L & 7;
            GLOAD_LDS(vg + (long)dr * T_ + k0 + ((gq ^ (dr & 7)) * 8),
                      &Vtile[bufi][L * 8]);
        }
    };

    STAGE(0, 0);
    int buf = 0;
    for (int kt = 0; kt < nkt; ++kt) {
        asm volatile("s_waitcnt vmcnt(0)" ::: "memory");    // tile kt (only in flight)
        __builtin_amdgcn_sched_barrier(0);
        __builtin_amdgcn_s_barrier();                        // buf^1 free, tile visible
        __builtin_amdgcn_sched_barrier(0);
        if (kt + 1 < nkt)
            STAGE(buf ^ 1, kt + 1);                          // covered by compute below

        const int k0 = kt * 64;
        if (k0 <= qw0 + 15) {
            // ---- QK^T: S[16q x 64k] ----
            f32x4 s[4];
            #pragma unroll
            for (int nt = 0; nt < 4; ++nt) s[nt] = (f32x4)(0.f);
            const int kkey = fr & 7;
            __builtin_amdgcn_s_setprio(1);
            #pragma unroll
            for (int c = 0; c < 8; ++c) {
                #pragma unroll
                for (int nt = 0; nt < 4; ++nt) {
                    const int kr = nt * 16 + fr;
                    half8 kf = *(const half8*)&Ktile[buf][(kr * 32 + ((c * 4 + g) ^ kkey)) * 8];
                    s[nt] = __builtin_amdgcn_mfma_f32_16x16x32_f16(qf[c], kf, s[nt], 0, 0, 0);
                }
            }
            __builtin_amdgcn_s_setprio(0);

            // ---- causal mask (log2 domain) ----
            const bool diag = (k0 + 63 > qw0);
            float sv[4][4];
            #pragma unroll
            for (int nt = 0; nt < 4; ++nt)
                #pragma unroll
                for (int reg = 0; reg < 4; ++reg) {
                    float v = s[nt][reg];
                    if (diag && (k0 + nt * 16 + fr > qw0 + g * 4 + reg)) v = -INFINITY;
                    sv[nt][reg] = v;
                }

            // ---- defer-max online softmax ----
            float pmax[4];
            #pragma unroll
            for (int reg = 0; reg < 4; ++reg)
                pmax[reg] = fmaxf(fmaxf(sv[0][reg], sv[1][reg]),
                                  fmaxf(sv[2][reg], sv[3][reg]));
            const bool ok = (pmax[0] <= mrow[0] + 8.f) && (pmax[1] <= mrow[1] + 8.f)
                         && (pmax[2] <= mrow[2] + 8.f) && (pmax[3] <= mrow[3] + 8.f);
            if (!__all(ok)) {
                #pragma unroll
                for (int reg = 0; reg < 4; ++reg) {
                    float tm = pmax[reg];
                    tm = fmaxf(tm, __shfl_xor(tm, 1));
                    tm = fmaxf(tm, __shfl_xor(tm, 2));
                    tm = fmaxf(tm, __shfl_xor(tm, 4));
                    tm = fmaxf(tm, __shfl_xor(tm, 8));
                    const float mnew = fmaxf(mrow[reg], tm);
                    const float alpha = exp2f(mrow[reg] - mnew);
                    mrow[reg] = mnew;
                    lrow[reg] *= alpha;
                    #pragma unroll
                    for (int dt = 0; dt < 16; ++dt) o[dt][reg] *= alpha;
                }
            }
            #pragma unroll
            for (int nt = 0; nt < 4; ++nt)
                #pragma unroll
                for (int reg = 0; reg < 4; ++reg) {
                    const float pp = exp2f(sv[nt][reg] - mrow[reg]);
                    lrow[reg] += pp;
                    Ps[w][(g * 4 + reg) * 72 + nt * 16 + fr] = f2h(pp);
                }

            // ---- P as A-frags (k 0..31 and 32..63) ----
            const half8 pf0 = *(const half8*)&Ps[w][fr * 72 + g * 8];
            const half8 pf1 = *(const half8*)&Ps[w][fr * 72 + 32 + g * 8];

            // ---- PV: O[16q x 256d] += P * V (two k-halves) ----
            __builtin_amdgcn_s_setprio(1);
            #pragma unroll
            for (int dt = 0; dt < 16; ++dt) {
                const int dr = dt * 16 + fr;
                const int key = dr & 7;
                half8 vf0 = *(const half8*)&Vtile[buf][(dr * 8 + (g ^ key)) * 8];
                o[dt] = __builtin_amdgcn_mfma_f32_16x16x32_f16(pf0, vf0, o[dt], 0, 0, 0);
                half8 vf1 = *(const half8*)&Vtile[buf][(dr * 8 + ((g + 4) ^ key)) * 8];
                o[dt] = __builtin_amdgcn_mfma_f32_16x16x32_f16(pf1, vf1, o[dt], 0, 0, 0);
            }
            __builtin_amdgcn_s_setprio(0);
        }
        buf ^= 1;
    }

    // ---- epilogue: reduce lrow across fr lanes, O /= l, write f16 ----
    float inv[4];
    #pragma unroll
    for (int reg = 0; reg < 4; ++reg) {
        float ps = lrow[reg];
        ps += __shfl_xor(ps, 1);
        ps += __shfl_xor(ps, 2);
        ps += __shfl_xor(ps, 4);
        ps += __shfl_xor(ps, 8);
        inv[reg] = 1.f / ps;
    }
    const long rowbase = ((long)b * T_ + qw0 + g * 4) * E_ + h * D_;
    #pragma unroll
    for (int reg = 0; reg < 4; ++reg) {
        unsigned short* dst = Z2h + rowbase + (long)reg * E_ + fr;
        #pragma unroll
        for (int dt = 0; dt < 16; ++dt)
            dst[dt * 16] = f2h(o[dt][reg] * inv[reg]);
    }
}

// ---------------------------------------------------------------------------
// d_in: keys, values, queries, Wk, Wq, Wv, Wo, bo (fp32)
// ws (f16): Kp|Vp(unused)|Qp|Vt | Z2h | weights
// ---------------------------------------------------------------------------
extern "C" void kernel_launch(void* const* d_in, const int* in_sizes, int n_in,
                              void* d_out, int out_size, void* d_ws, size_t ws_size,
                              hipStream_t stream)
{
    const float* Xk = (const float*)d_in[0];
    const float* Xv = (const float*)d_in[1];
    const float* Xq = (const float*)d_in[2];
    const float* Wk = (const float*)d_in[3];
    const float* Wq = (const float*)d_in[4];
    const float* Wv = (const float*)d_in[5];
    const float* Wo = (const float*)d_in[6];
    const float* bo = (const float*)d_in[7];
    float* out = (float*)d_out;

    const size_t phd = (size_t)B_ * H_ * T_ * D_;
    const size_t wsz = (size_t)H_ * E_ * D_;
    unsigned short* Kp  = (unsigned short*)d_ws;
    unsigned short* Vp  = Kp + phd;                 // unused
    unsigned short* Qp  = Vp + phd;
    unsigned short* Vt  = Qp + phd;
    unsigned short* Z2h = Vt + phd;
    unsigned short* WTk = Z2h + (size_t)B_ * T_ * E_;
    unsigned short* WTq = WTk + wsz;
    unsigned short* WTv = WTq + wsz;
    unsigned short* WoT = WTv + wsz;

    dim3 blk(256);

    dim3 gtw(E_ / 32, E_ / 32, 10);
    transpose_cast_all<<<gtw, blk, 0, stream>>>(Wk, Wq, Wv, Wo, WTk, WTq, WTv, WoT);

    dim3 gproj(D_ / 128, T_ / 128, 36);
    qkv_proj<<<gproj, blk, 0, stream>>>(Xk, Xv, Xq, WTk, WTv, WTq, Kp, Vt, Qp);

    // BK=64 8-wave flash attention -> Z2h f16 [B][T][H*D]
    dim3 gf(16 * B_ * H_);                          // 192 blocks x 8 waves
    dim3 fblk(512);
    flash_lds<<<gf, fblk, 0, stream>>>(Qp, Kp, Vt, Z2h,
                                       0.022097086912079608f * LOG2E);

    dim3 gout(E_ / 128, (B_ * T_) / 128, 1);
    gemm_mfma<false, false><<<gout, blk, 0, stream>>>(Z2h, WoT, out, bo, E_, 1, E_, E_,
                                                      0L, 0L, 0L);
}